// Round 1
// baseline (162.483 us; speedup 1.0000x reference)
//
#include <hip/hip_runtime.h>
#include <hip/hip_bf16.h>

typedef __bf16 bf16x8 __attribute__((ext_vector_type(8)));
typedef __bf16 bf16x4 __attribute__((ext_vector_type(4)));
typedef float  f32x4  __attribute__((ext_vector_type(4)));

constexpr int NN = 16384;
constexpr int EE = 64;
constexpr int DD = 128;
constexpr int BM = 128;   // n-rows per block

// One block = one (n-tile, expert) pair. 256 threads = 4 waves.
// LDS: As[128][128] bf16 (x tile), Bs[128][128] bf16 (W[e]^T), both XOR-swizzled.
__global__ __launch_bounds__(256, 2)
void experts_gemm(const float* __restrict__ X,
                  const float* __restrict__ W,
                  const float* __restrict__ Bias,
                  float* __restrict__ O)
{
    __shared__ __align__(16) char lds[BM*DD*2 + DD*DD*2];   // 64 KiB
    __bf16* As = (__bf16*)lds;                 // [n][d] swizzled
    __bf16* Bs = (__bf16*)(lds + BM*DD*2);     // [f][d] swizzled (W^T)

    const int t   = threadIdx.x;
    const int bid = blockIdx.x;
    const int e   = bid & (EE - 1);
    const int nt  = bid >> 6;
    const int n0  = nt * BM;

    // ---- stage A: X[n0..n0+127][:] -> bf16 LDS (swizzled) ----
    {
        const float4* Xg = (const float4*)(X + (size_t)n0 * DD);
        #pragma unroll
        for (int i = 0; i < 16; ++i) {          // 4096 float4 / 256 thr
            int ft = i * 256 + t;
            float4 v = Xg[ft];
            int n  = ft >> 5;                   // 32 float4 per row
            int d0 = (ft & 31) << 2;
            bf16x4 p;
            p[0] = (__bf16)v.x; p[1] = (__bf16)v.y;
            p[2] = (__bf16)v.z; p[3] = (__bf16)v.w;
            int off = n * 256 + d0 * 2;
            off ^= (n & 7) << 4;                // st-swizzle, keeps 8B alignment
            *(bf16x4*)((char*)As + off) = p;
        }
    }
    // ---- stage B: W[e][d][f] -> Bs[f][d] bf16 (transpose in reg, swizzled) ----
    {
        const float4* Wg = (const float4*)(W + (size_t)e * DD * DD);
        #pragma unroll
        for (int i = 0; i < 4; ++i) {           // 1024 4x4 blocks / 256 thr
            int bb = i * 256 + t;
            int db = bb >> 5;                   // d-block 0..31
            int fb = bb & 31;                   // f-block 0..31
            float4 r0 = Wg[(db*4 + 0)*32 + fb];
            float4 r1 = Wg[(db*4 + 1)*32 + fb];
            float4 r2 = Wg[(db*4 + 2)*32 + fb];
            float4 r3 = Wg[(db*4 + 3)*32 + fb];
            const float* q0 = (const float*)&r0;
            const float* q1 = (const float*)&r1;
            const float* q2 = (const float*)&r2;
            const float* q3 = (const float*)&r3;
            #pragma unroll
            for (int j = 0; j < 4; ++j) {
                bf16x4 p;
                p[0] = (__bf16)q0[j]; p[1] = (__bf16)q1[j];
                p[2] = (__bf16)q2[j]; p[3] = (__bf16)q3[j];
                int f = fb * 4 + j;
                int off = f * 256 + db * 8;
                off ^= (f & 7) << 4;
                *(bf16x4*)((char*)Bs + off) = p;
            }
        }
    }
    __syncthreads();

    const int lane = t & 63;
    const int w    = t >> 6;
    const int wr   = w >> 1;      // wave row (0..1), 64 n-rows each
    const int wc   = w & 1;       // wave col (0..1), 64 f-cols each
    const int l15  = lane & 15;
    const int kg   = lane >> 4;   // k-group 0..3

    f32x4 acc[4][4];
    #pragma unroll
    for (int m = 0; m < 4; ++m)
        #pragma unroll
        for (int n = 0; n < 4; ++n) {
            acc[m][n][0] = 0.f; acc[m][n][1] = 0.f;
            acc[m][n][2] = 0.f; acc[m][n][3] = 0.f;
        }

    float bias[4];
    #pragma unroll
    for (int n = 0; n < 4; ++n)
        bias[n] = Bias[e * DD + wc * 64 + n * 16 + l15];

    #pragma unroll
    for (int kk = 0; kk < 4; ++kk) {
        int koff = kk * 32 + kg * 8;
        bf16x8 a[4], b[4];
        #pragma unroll
        for (int m = 0; m < 4; ++m) {
            int row = wr * 64 + m * 16 + l15;
            int off = row * 256 + koff * 2;
            off ^= (row & 7) << 4;
            a[m] = *(const bf16x8*)((const char*)As + off);
        }
        #pragma unroll
        for (int n = 0; n < 4; ++n) {
            int col = wc * 64 + n * 16 + l15;
            int off = col * 256 + koff * 2;
            off ^= (col & 7) << 4;
            b[n] = *(const bf16x8*)((const char*)Bs + off);
        }
        #pragma unroll
        for (int m = 0; m < 4; ++m)
            #pragma unroll
            for (int n = 0; n < 4; ++n)
                acc[m][n] = __builtin_amdgcn_mfma_f32_16x16x32_bf16(
                    a[m], b[n], acc[m][n], 0, 0, 0);
    }

    // ---- epilogue: += bias, store f32. C/D layout: col=lane&15, row=kg*4+r ----
    float* Op = O + (size_t)n0 * (EE * DD) + (size_t)e * DD;
    #pragma unroll
    for (int m = 0; m < 4; ++m) {
        #pragma unroll
        for (int n = 0; n < 4; ++n) {
            int cg = wc * 64 + n * 16 + l15;
            #pragma unroll
            for (int r = 0; r < 4; ++r) {
                int rg = wr * 64 + m * 16 + kg * 4 + r;
                Op[(size_t)rg * (EE * DD) + cg] = acc[m][n][r] + bias[n];
            }
        }
    }
}

extern "C" void kernel_launch(void* const* d_in, const int* in_sizes, int n_in,
                              void* d_out, int out_size, void* d_ws, size_t ws_size,
                              hipStream_t stream) {
    const float* X = (const float*)d_in[0];
    const float* W = (const float*)d_in[1];
    const float* B = (const float*)d_in[2];
    float* O = (float*)d_out;
    dim3 grid((NN / BM) * EE);   // 128 n-tiles * 64 experts = 8192 blocks
    dim3 block(256);
    experts_gemm<<<grid, block, 0, stream>>>(X, W, B, O);
}